// Round 1
// baseline (5804.259 us; speedup 1.0000x reference)
//
#include <hip/hip_runtime.h>
#include <hip/hip_bf16.h>

// RITS recurrent imputation, B=1024 T=100 F=64 H=256.
// Design: batch rows are independent through the recurrence (losses are pure
// accumulators) -> persistent kernel, 64 blocks x 16 rows, T-loop in-kernel,
// no grid sync. bf16 MFMA 16x16x32 for all GEMMs, fp32 state/elementwise.
// Per-step per-block loss partials -> ws; tiny finalize kernel.

#define Bz 1024
#define Tz 100
#define Fz 64
#define Hz 256
#define GRID 64
#define RPB 16

typedef __attribute__((ext_vector_type(8))) short short8;
typedef __attribute__((ext_vector_type(4))) float floatx4;
typedef __hip_bfloat16 bf16;

#define MFMA16(a, b, c) __builtin_amdgcn_mfma_f32_16x16x32_bf16((a), (b), (c), 0, 0, 0)

__device__ __forceinline__ float sigmf(float x) { return 1.0f / (1.0f + __expf(-x)); }

// ws bf16 layout (elements):
// Wdh[256x64]@0, Whist[64x256]@16384, Wfeatm[64x64]@32768, Wcomb[64x128]@36864,
// Wih[1024x128]@45056, Whh[1024x256]@176128 ; total 438272 bf16.
// then f32: wdx_diag[64] @byte 876544, lossbuf[64*100*4] @byte 876800.

__global__ void rits_convert(const float* __restrict__ Wdh, const float* __restrict__ Wdx,
                             const float* __restrict__ Whist, const float* __restrict__ Wfeat,
                             const float* __restrict__ Wcomb, const float* __restrict__ Wih,
                             const float* __restrict__ Whh, bf16* __restrict__ wsbf,
                             float* __restrict__ wdxd) {
    int idx = blockIdx.x * blockDim.x + threadIdx.x;
    if (idx < 64) wdxd[idx] = Wdx[idx * 65];  // diag of W_dx
    if (idx >= 438272) return;
    float v;
    if (idx < 16384) v = Wdh[idx];
    else if (idx < 32768) v = Whist[idx - 16384];
    else if (idx < 36864) { int i = idx - 32768; v = ((i >> 6) == (i & 63)) ? 0.0f : Wfeat[i]; }
    else if (idx < 45056) v = Wcomb[idx - 36864];
    else if (idx < 176128) v = Wih[idx - 45056];
    else v = Whh[idx - 176128];
    wsbf[idx] = __float2bfloat16(v);
}

__global__ __launch_bounds__(256, 1) void rits_main(
    const float* __restrict__ X, const float* __restrict__ Mm, const float* __restrict__ Dd,
    const float* __restrict__ b_dh, const float* __restrict__ b_dx,
    const float* __restrict__ b_hist, const float* __restrict__ b_feat,
    const float* __restrict__ b_comb, const float* __restrict__ b_ih,
    const float* __restrict__ b_hh,
    const bf16* __restrict__ Wdh, const bf16* __restrict__ Whist,
    const bf16* __restrict__ Wfeatm, const bf16* __restrict__ Wcomb,
    const bf16* __restrict__ Wih, const bf16* __restrict__ Whh,
    const float* __restrict__ wdxd, float* __restrict__ lossbuf, float* __restrict__ out) {
    // ---- LDS (static, ~128.7 KB; gfx950 allows 160 KB/workgroup) ----
    __shared__ __align__(16) float sh_h[RPB * 257];   // fp32 h state (pad 257)
    __shared__ __align__(16) float sh_c[RPB * 257];   // fp32 c state
    __shared__ __align__(16) bf16 sh_hbf[RPB * 264];  // decayed h, bf16, A-operand (pad 264)
    __shared__ __align__(16) float sh_x[RPB * 64];
    __shared__ __align__(16) float sh_m[RPB * 64];
    __shared__ __align__(16) bf16 sh_dbf[RPB * 72];    // d bf16 (pad 72)
    __shared__ __align__(16) bf16 sh_xcbf[RPB * 72];   // x_c bf16
    __shared__ __align__(16) bf16 sh_gmbf[RPB * 136];  // [gamma_x | m] bf16 (pad 136)
    __shared__ __align__(16) bf16 sh_inbf[RPB * 136];  // [c_c | m] bf16
    __shared__ __align__(16) float sh_g[4 * RPB * 257];  // transformed gates i,f,g,o
    __shared__ __align__(16) float sh_red[16];

    const int tid = threadIdx.x;
    const int lane = tid & 63;
    const int wid = tid >> 6;   // wave id 0..3 (= gate type in P5)
    const int l16 = lane & 15;
    const int q = lane >> 4;    // quad 0..3
    const int b0 = blockIdx.x * RPB;
    const int lrow = tid >> 4;        // 0..15 (row for elementwise)
    const int lf4 = (tid & 15) * 4;   // 0..60

    for (int i = tid; i < RPB * 257; i += 256) { sh_h[i] = 0.0f; sh_c[i] = 0.0f; }
    __syncthreads();

    const int colF = wid * 16 + l16;  // F-column owned in P2/P34

    for (int t = 0; t < Tz; ++t) {
        // ---- P0: load x,m,d tile; gamma_x; prefill m halves ----
        size_t gidx = ((size_t)(b0 + lrow) * Tz + t) * Fz + lf4;
        float4 xv = *(const float4*)(X + gidx);
        float4 mv = *(const float4*)(Mm + gidx);
        float4 dv = *(const float4*)(Dd + gidx);
        *(float4*)(sh_x + lrow * 64 + lf4) = xv;
        *(float4*)(sh_m + lrow * 64 + lf4) = mv;
        float summ = mv.x + mv.y + mv.z + mv.w;
        {
            float dd[4] = {dv.x, dv.y, dv.z, dv.w};
            float mm[4] = {mv.x, mv.y, mv.z, mv.w};
#pragma unroll
            for (int j = 0; j < 4; ++j) {
                int f = lf4 + j;
                float gx = __expf(-fmaxf(dd[j] * wdxd[f] + b_dx[f], 0.0f));
                sh_gmbf[lrow * 136 + f] = __float2bfloat16(gx);
                bf16 mb = __float2bfloat16(mm[j]);
                sh_gmbf[lrow * 136 + 64 + f] = mb;
                sh_inbf[lrow * 136 + 64 + f] = mb;
                sh_dbf[lrow * 72 + f] = __float2bfloat16(dd[j]);
            }
        }
        __syncthreads();

        // ---- P1: gamma_h = exp(-relu(d@Wdh^T+b)); h *= gamma_h ----
        {
            short8 a0 = *(const short8*)(sh_dbf + l16 * 72 + q * 8);
            short8 a1 = *(const short8*)(sh_dbf + l16 * 72 + 32 + q * 8);
#pragma unroll
            for (int nt = 0; nt < 4; ++nt) {
                int col = wid * 64 + nt * 16 + l16;  // H index
                floatx4 acc = {0.0f, 0.0f, 0.0f, 0.0f};
                acc = MFMA16(a0, *(const short8*)(Wdh + col * 64 + q * 8), acc);
                acc = MFMA16(a1, *(const short8*)(Wdh + col * 64 + 32 + q * 8), acc);
                float bd = b_dh[col];
#pragma unroll
                for (int r = 0; r < 4; ++r) {
                    int row = q * 4 + r;
                    float g = __expf(-fmaxf(acc[r] + bd, 0.0f));
                    float hn = sh_h[row * 257 + col] * g;
                    sh_h[row * 257 + col] = hn;
                    sh_hbf[row * 264 + col] = __float2bfloat16(hn);
                }
            }
        }
        __syncthreads();

        // ---- P2: x_h = h@Whist^T + b; loss1; x_c ----
        float xh[4];
        float l1 = 0.0f, l2 = 0.0f, l3 = 0.0f;
        {
            floatx4 acc = {0.0f, 0.0f, 0.0f, 0.0f};
#pragma unroll
            for (int kb = 0; kb < 8; ++kb) {
                short8 a = *(const short8*)(sh_hbf + l16 * 264 + kb * 32 + q * 8);
                short8 b = *(const short8*)(Whist + colF * 256 + kb * 32 + q * 8);
                acc = MFMA16(a, b, acc);
            }
            float bh = b_hist[colF];
#pragma unroll
            for (int r = 0; r < 4; ++r) {
                int row = q * 4 + r;
                xh[r] = acc[r] + bh;
                float xx = sh_x[row * 64 + colF], mm = sh_m[row * 64 + colF];
                l1 += fabsf(xh[r] - xx) * mm;
                float xc = mm * xx + (1.0f - mm) * xh[r];
                sh_xcbf[row * 72 + colF] = __float2bfloat16(xc);
            }
        }
        __syncthreads();

        // ---- P3/4: z_h, alpha, c_h, imputed write, c_c ----
        {
            floatx4 accz = {0.0f, 0.0f, 0.0f, 0.0f};
#pragma unroll
            for (int kb = 0; kb < 2; ++kb) {
                short8 a = *(const short8*)(sh_xcbf + l16 * 72 + kb * 32 + q * 8);
                short8 b = *(const short8*)(Wfeatm + colF * 64 + kb * 32 + q * 8);
                accz = MFMA16(a, b, accz);
            }
            floatx4 acca = {0.0f, 0.0f, 0.0f, 0.0f};
#pragma unroll
            for (int kb = 0; kb < 4; ++kb) {
                short8 a = *(const short8*)(sh_gmbf + l16 * 136 + kb * 32 + q * 8);
                short8 b = *(const short8*)(Wcomb + colF * 128 + kb * 32 + q * 8);
                acca = MFMA16(a, b, acca);
            }
            float bf_ = b_feat[colF], bc = b_comb[colF];
#pragma unroll
            for (int r = 0; r < 4; ++r) {
                int row = q * 4 + r;
                float xx = sh_x[row * 64 + colF], mm = sh_m[row * 64 + colF];
                float z = accz[r] + bf_;
                l2 += fabsf(z - xx) * mm;
                float al = sigmf(acca[r] + bc);
                float ch = al * z + (1.0f - al) * xh[r];
                l3 += fabsf(ch - xx) * mm;
                float imp = mm * xx + (1.0f - mm) * ch;  // == c_c as well
                out[((size_t)(b0 + row) * Tz + t) * Fz + colF] = imp;
                sh_inbf[row * 136 + colF] = __float2bfloat16(imp);
            }
        }
        __syncthreads();

        // ---- P5: gates = [c_c,m]@Wih^T + h@Whh^T + b; wave w owns gate w ----
        {
            floatx4 acc[16];
#pragma unroll
            for (int i = 0; i < 16; ++i) acc[i] = (floatx4){0.0f, 0.0f, 0.0f, 0.0f};
#pragma unroll
            for (int kb = 0; kb < 4; ++kb) {
                short8 a = *(const short8*)(sh_inbf + l16 * 136 + kb * 32 + q * 8);
#pragma unroll
                for (int nt = 0; nt < 16; ++nt) {
                    int n = wid * 256 + nt * 16 + l16;
                    short8 b = *(const short8*)(Wih + n * 128 + kb * 32 + q * 8);
                    acc[nt] = MFMA16(a, b, acc[nt]);
                }
            }
#pragma unroll
            for (int kb = 0; kb < 8; ++kb) {
                short8 a = *(const short8*)(sh_hbf + l16 * 264 + kb * 32 + q * 8);
#pragma unroll
                for (int nt = 0; nt < 16; ++nt) {
                    int n = wid * 256 + nt * 16 + l16;
                    short8 b = *(const short8*)(Whh + n * 256 + kb * 32 + q * 8);
                    acc[nt] = MFMA16(a, b, acc[nt]);
                }
            }
#pragma unroll
            for (int nt = 0; nt < 16; ++nt) {
                int gn = wid * 256 + nt * 16 + l16;
                float bb = b_ih[gn] + b_hh[gn];
#pragma unroll
                for (int r = 0; r < 4; ++r) {
                    int row = q * 4 + r;
                    float v = acc[nt][r] + bb;
                    float tv = (wid == 2) ? tanhf(v) : sigmf(v);
                    sh_g[wid * (RPB * 257) + row * 257 + nt * 16 + l16] = tv;
                }
            }
        }
        __syncthreads();

        // ---- P6: c,h update + per-step loss reduce ----
        {
            int j0 = tid & 15;
#pragma unroll
            for (int jj = 0; jj < 16; ++jj) {
                int j = j0 + jj * 16;
                int gi = lrow * 257 + j;
                float Ig = sh_g[gi];
                float Fg = sh_g[RPB * 257 + gi];
                float Gg = sh_g[2 * RPB * 257 + gi];
                float Og = sh_g[3 * RPB * 257 + gi];
                float cn = Fg * sh_c[gi] + Ig * Gg;
                sh_c[gi] = cn;
                sh_h[gi] = Og * tanhf(cn);
            }
            float v0 = summ, v1 = l1, v2 = l2, v3 = l3;
#pragma unroll
            for (int off = 32; off; off >>= 1) {
                v0 += __shfl_xor(v0, off, 64);
                v1 += __shfl_xor(v1, off, 64);
                v2 += __shfl_xor(v2, off, 64);
                v3 += __shfl_xor(v3, off, 64);
            }
            if (lane == 0) {
                sh_red[wid * 4 + 0] = v0; sh_red[wid * 4 + 1] = v1;
                sh_red[wid * 4 + 2] = v2; sh_red[wid * 4 + 3] = v3;
            }
        }
        __syncthreads();
        if (tid == 0) {
            float* lb = lossbuf + ((size_t)blockIdx.x * Tz + t) * 4;
            lb[0] = sh_red[0] + sh_red[4] + sh_red[8] + sh_red[12];
            lb[1] = sh_red[1] + sh_red[5] + sh_red[9] + sh_red[13];
            lb[2] = sh_red[2] + sh_red[6] + sh_red[10] + sh_red[14];
            lb[3] = sh_red[3] + sh_red[7] + sh_red[11] + sh_red[15];
        }
    }
}

__global__ void rits_finalize(const float* __restrict__ lossbuf, float* __restrict__ out) {
    __shared__ float m1[Tz], m2[Tz], m3[Tz];
    int t = threadIdx.x;
    if (t < Tz) {
        float s0 = 0.0f, s1 = 0.0f, s2 = 0.0f, s3 = 0.0f;
        for (int g = 0; g < GRID; ++g) {
            const float* lb = lossbuf + ((size_t)g * Tz + t) * 4;
            s0 += lb[0]; s1 += lb[1]; s2 += lb[2]; s3 += lb[3];
        }
        float inv = 1.0f / (s0 + 1e-9f);
        m1[t] = s1 * inv; m2[t] = s2 * inv; m3[t] = s3 * inv;
    }
    __syncthreads();
    if (t == 0) {
        float rm = 0.0f, rl = 0.0f;
        for (int i = 0; i < Tz; ++i) {  // literal replay of reference accumulation
            rl += m1[i]; rl += m2[i]; rm += m3[i]; rl += rm;
        }
        out[(size_t)Bz * Tz * Fz] = rm / (float)Tz;
        out[(size_t)Bz * Tz * Fz + 1] = rl / (3.0f * (float)Tz);
    }
}

extern "C" void kernel_launch(void* const* d_in, const int* in_sizes, int n_in,
                              void* d_out, int out_size, void* d_ws, size_t ws_size,
                              hipStream_t stream) {
    const float* X = (const float*)d_in[0];
    const float* Mm = (const float*)d_in[1];
    const float* Dd = (const float*)d_in[2];
    const float* Wdh = (const float*)d_in[3];
    const float* b_dh = (const float*)d_in[4];
    const float* Wdx = (const float*)d_in[5];
    const float* b_dx = (const float*)d_in[6];
    const float* Whist = (const float*)d_in[7];
    const float* b_hist = (const float*)d_in[8];
    const float* Wfeat = (const float*)d_in[9];
    const float* b_feat = (const float*)d_in[10];
    const float* Wcomb = (const float*)d_in[11];
    const float* b_comb = (const float*)d_in[12];
    const float* Wih = (const float*)d_in[13];
    const float* b_ih = (const float*)d_in[14];
    const float* Whh = (const float*)d_in[15];
    const float* b_hh = (const float*)d_in[16];
    float* out = (float*)d_out;

    bf16* wsbf = (bf16*)d_ws;
    float* wdxd = (float*)((char*)d_ws + (size_t)438272 * 2);
    float* lossbuf = wdxd + 64;

    rits_convert<<<1712, 256, 0, stream>>>(Wdh, Wdx, Whist, Wfeat, Wcomb, Wih, Whh, wsbf, wdxd);
    rits_main<<<GRID, 256, 0, stream>>>(X, Mm, Dd, b_dh, b_dx, b_hist, b_feat, b_comb, b_ih, b_hh,
                                        wsbf + 0, wsbf + 16384, wsbf + 32768, wsbf + 36864,
                                        wsbf + 45056, wsbf + 176128, wdxd, lossbuf, out);
    rits_finalize<<<1, 128, 0, stream>>>(lossbuf, out);
}

// Round 2
// 3074.897 us; speedup vs baseline: 1.8876x; 1.8876x over previous
//
#include <hip/hip_runtime.h>
#include <hip/hip_bf16.h>

// RITS recurrent imputation, B=1024 T=100 F=64 H=256.
// Round 2: 64 persistent blocks x 1024 threads (16 waves, 4/SIMD).
// Each wave owns a 16-wide h-column slice across all 4 LSTM gates in P5 and
// updates c/h in-register (no gate buffer, no P6). VGPR capped at 128 via
// __launch_bounds__(1024,4) (required: 16 waves/CU * 128 = 2048 VGPR pool).

#define Bz 1024
#define Tz 100
#define Fz 64
#define Hz 256
#define GRID 64
#define RPB 16

typedef __attribute__((ext_vector_type(8))) short short8;
typedef __attribute__((ext_vector_type(4))) float floatx4;
typedef __hip_bfloat16 bf16;

#define MFMA16(a, b, c) __builtin_amdgcn_mfma_f32_16x16x32_bf16((a), (b), (c), 0, 0, 0)

__device__ __forceinline__ float sigmf(float x) { return 1.0f / (1.0f + __expf(-x)); }

// ws bf16 layout (elements):
// Wdh[256x64]@0, Whist[64x256]@16384, Wfeatm[64x64]@32768, Wcomb[64x128]@36864,
// Wih[1024x128]@45056, Whh[1024x256]@176128 ; total 438272 bf16.
// then f32: wdx_diag[64], lossbuf[64*100*4].

__global__ void rits_convert(const float* __restrict__ Wdh, const float* __restrict__ Wdx,
                             const float* __restrict__ Whist, const float* __restrict__ Wfeat,
                             const float* __restrict__ Wcomb, const float* __restrict__ Wih,
                             const float* __restrict__ Whh, bf16* __restrict__ wsbf,
                             float* __restrict__ wdxd) {
    int idx = blockIdx.x * blockDim.x + threadIdx.x;
    if (idx < 64) wdxd[idx] = Wdx[idx * 65];  // diag of W_dx
    if (idx >= 438272) return;
    float v;
    if (idx < 16384) v = Wdh[idx];
    else if (idx < 32768) v = Whist[idx - 16384];
    else if (idx < 36864) { int i = idx - 32768; v = ((i >> 6) == (i & 63)) ? 0.0f : Wfeat[i]; }
    else if (idx < 45056) v = Wcomb[idx - 36864];
    else if (idx < 176128) v = Wih[idx - 45056];
    else v = Whh[idx - 176128];
    wsbf[idx] = __float2bfloat16(v);
}

__global__ __launch_bounds__(1024, 4) void rits_main(
    const float* __restrict__ X, const float* __restrict__ Mm, const float* __restrict__ Dd,
    const float* __restrict__ b_dh, const float* __restrict__ b_dx,
    const float* __restrict__ b_hist, const float* __restrict__ b_feat,
    const float* __restrict__ b_comb, const float* __restrict__ b_ih,
    const float* __restrict__ b_hh,
    const bf16* __restrict__ Wdh, const bf16* __restrict__ Whist,
    const bf16* __restrict__ Wfeatm, const bf16* __restrict__ Wcomb,
    const bf16* __restrict__ Wih, const bf16* __restrict__ Whh,
    const float* __restrict__ wdxd, float* __restrict__ lossbuf, float* __restrict__ out) {
    // ---- LDS (~63 KB) ----
    __shared__ __align__(16) float sh_h[RPB * 257];   // fp32 h state (pad 257)
    __shared__ __align__(16) float sh_c[RPB * 257];   // fp32 c state
    __shared__ __align__(16) bf16 sh_hbf[RPB * 264];  // decayed h, bf16 A-operand (pad 264)
    __shared__ __align__(16) float sh_x[RPB * 64];
    __shared__ __align__(16) float sh_m[RPB * 64];
    __shared__ __align__(16) bf16 sh_dbf[RPB * 72];    // d bf16 (pad 72)
    __shared__ __align__(16) bf16 sh_xcbf[RPB * 72];   // x_c bf16
    __shared__ __align__(16) bf16 sh_gmbf[RPB * 136];  // [gamma_x | m] bf16 (pad 136)
    __shared__ __align__(16) bf16 sh_inbf[RPB * 136];  // [c_c | m] bf16
    __shared__ __align__(16) float sh_lred[16];        // waves 0-3: {l1,l2,l3} x4
    __shared__ __align__(16) float sh_msum[16];

    const int tid = threadIdx.x;
    const int lane = tid & 63;
    const int wid = tid >> 6;   // wave id 0..15
    const int l16 = lane & 15;
    const int q = lane >> 4;    // quad 0..3
    const int b0 = blockIdx.x * RPB;

    for (int i = tid; i < RPB * 257; i += 1024) { sh_h[i] = 0.0f; sh_c[i] = 0.0f; }
    __syncthreads();

    const int colH = wid * 16 + l16;  // H column owned in P1/P5 (0..255)
    const int colF = colH;            // F column owned in P2/P34 (waves 0-3)

    for (int t = 0; t < Tz; ++t) {
        // ---- P0: load x,m,d (1 elem/thread, coalesced); gamma_x; m halves ----
        {
            int row = wid, f = lane;
            size_t g = ((size_t)(b0 + row) * Tz + t) * Fz + f;
            float xv = X[g], mv = Mm[g], dv = Dd[g];
            sh_x[row * 64 + f] = xv;
            sh_m[row * 64 + f] = mv;
            float gx = __expf(-fmaxf(dv * wdxd[f] + b_dx[f], 0.0f));
            sh_gmbf[row * 136 + f] = __float2bfloat16(gx);
            bf16 mb = __float2bfloat16(mv);
            sh_gmbf[row * 136 + 64 + f] = mb;
            sh_inbf[row * 136 + 64 + f] = mb;
            sh_dbf[row * 72 + f] = __float2bfloat16(dv);
            float v0 = mv;
#pragma unroll
            for (int off = 32; off; off >>= 1) v0 += __shfl_xor(v0, off, 64);
            if (lane == 0) sh_msum[wid] = v0;
        }
        __syncthreads();  // bar A

        // ---- P1: gamma_h; h *= gamma_h (wave w owns H cols [16w,16w+16)) ----
        {
            short8 a0 = *(const short8*)(sh_dbf + l16 * 72 + q * 8);
            short8 a1 = *(const short8*)(sh_dbf + l16 * 72 + 32 + q * 8);
            floatx4 acc = {0.0f, 0.0f, 0.0f, 0.0f};
            acc = MFMA16(a0, *(const short8*)(Wdh + colH * 64 + q * 8), acc);
            acc = MFMA16(a1, *(const short8*)(Wdh + colH * 64 + 32 + q * 8), acc);
            float bd = b_dh[colH];
#pragma unroll
            for (int r = 0; r < 4; ++r) {
                int row = q * 4 + r;
                float g = __expf(-fmaxf(acc[r] + bd, 0.0f));
                float hn = sh_h[row * 257 + colH] * g;
                sh_h[row * 257 + colH] = hn;
                sh_hbf[row * 264 + colH] = __float2bfloat16(hn);
            }
        }
        __syncthreads();  // bar B

        // ---- P2: x_h = h@Whist^T + b (waves 0-3); loss1; x_c ----
        float xh[4];
        float l1 = 0.0f, l2 = 0.0f, l3 = 0.0f;
        if (wid < 4) {
            floatx4 acc = {0.0f, 0.0f, 0.0f, 0.0f};
#pragma unroll
            for (int kb = 0; kb < 8; ++kb) {
                short8 a = *(const short8*)(sh_hbf + l16 * 264 + kb * 32 + q * 8);
                short8 b = *(const short8*)(Whist + colF * 256 + kb * 32 + q * 8);
                acc = MFMA16(a, b, acc);
            }
            float bh = b_hist[colF];
#pragma unroll
            for (int r = 0; r < 4; ++r) {
                int row = q * 4 + r;
                xh[r] = acc[r] + bh;
                float xx = sh_x[row * 64 + colF], mm = sh_m[row * 64 + colF];
                l1 += fabsf(xh[r] - xx) * mm;
                float xc = mm * xx + (1.0f - mm) * xh[r];
                sh_xcbf[row * 72 + colF] = __float2bfloat16(xc);
            }
        }
        __syncthreads();  // bar C

        // ---- P3/4: z_h, alpha, c_h, imputed write, c_c (waves 0-3) ----
        if (wid < 4) {
            floatx4 accz = {0.0f, 0.0f, 0.0f, 0.0f};
#pragma unroll
            for (int kb = 0; kb < 2; ++kb) {
                short8 a = *(const short8*)(sh_xcbf + l16 * 72 + kb * 32 + q * 8);
                short8 b = *(const short8*)(Wfeatm + colF * 64 + kb * 32 + q * 8);
                accz = MFMA16(a, b, accz);
            }
            floatx4 acca = {0.0f, 0.0f, 0.0f, 0.0f};
#pragma unroll
            for (int kb = 0; kb < 4; ++kb) {
                short8 a = *(const short8*)(sh_gmbf + l16 * 136 + kb * 32 + q * 8);
                short8 b = *(const short8*)(Wcomb + colF * 128 + kb * 32 + q * 8);
                acca = MFMA16(a, b, acca);
            }
            float bf_ = b_feat[colF], bc = b_comb[colF];
#pragma unroll
            for (int r = 0; r < 4; ++r) {
                int row = q * 4 + r;
                float xx = sh_x[row * 64 + colF], mm = sh_m[row * 64 + colF];
                float z = accz[r] + bf_;
                l2 += fabsf(z - xx) * mm;
                float al = sigmf(acca[r] + bc);
                float ch = al * z + (1.0f - al) * xh[r];
                l3 += fabsf(ch - xx) * mm;
                float imp = mm * xx + (1.0f - mm) * ch;  // == c_c
                out[((size_t)(b0 + row) * Tz + t) * Fz + colF] = imp;
                sh_inbf[row * 136 + colF] = __float2bfloat16(imp);
            }
            float v1 = l1, v2 = l2, v3 = l3;
#pragma unroll
            for (int off = 32; off; off >>= 1) {
                v1 += __shfl_xor(v1, off, 64);
                v2 += __shfl_xor(v2, off, 64);
                v3 += __shfl_xor(v3, off, 64);
            }
            if (lane == 0) {
                sh_lred[wid * 4 + 0] = v1;
                sh_lred[wid * 4 + 1] = v2;
                sh_lred[wid * 4 + 2] = v3;
            }
        }
        __syncthreads();  // bar D

        // loss write (one thread; overlaps with P5 issue)
        if (tid == 0) {
            float s0 = 0.0f;
#pragma unroll
            for (int i = 0; i < 16; ++i) s0 += sh_msum[i];
            float* lb = lossbuf + ((size_t)blockIdx.x * Tz + t) * 4;
            lb[0] = s0;
            lb[1] = sh_lred[0] + sh_lred[4] + sh_lred[8] + sh_lred[12];
            lb[2] = sh_lred[1] + sh_lred[5] + sh_lred[9] + sh_lred[13];
            lb[3] = sh_lred[2] + sh_lred[6] + sh_lred[10] + sh_lred[14];
        }

        // ---- P5: gates + LSTM update. Wave w owns h cols [16w,16w+16) for
        // ALL 4 gates -> updates c,h directly, no gate staging buffer. ----
        {
            floatx4 acc[4];
#pragma unroll
            for (int g = 0; g < 4; ++g) acc[g] = (floatx4){0.0f, 0.0f, 0.0f, 0.0f};
#pragma unroll
            for (int kb = 0; kb < 4; ++kb) {
                short8 a = *(const short8*)(sh_inbf + l16 * 136 + kb * 32 + q * 8);
#pragma unroll
                for (int g = 0; g < 4; ++g) {
                    int n = g * 256 + colH;
                    short8 b = *(const short8*)(Wih + n * 128 + kb * 32 + q * 8);
                    acc[g] = MFMA16(a, b, acc[g]);
                }
            }
#pragma unroll
            for (int kb = 0; kb < 8; ++kb) {
                short8 a = *(const short8*)(sh_hbf + l16 * 264 + kb * 32 + q * 8);
#pragma unroll
                for (int g = 0; g < 4; ++g) {
                    int n = g * 256 + colH;
                    short8 b = *(const short8*)(Whh + n * 256 + kb * 32 + q * 8);
                    acc[g] = MFMA16(a, b, acc[g]);
                }
            }
            float bi = b_ih[colH] + b_hh[colH];
            float bf2 = b_ih[256 + colH] + b_hh[256 + colH];
            float bg = b_ih[512 + colH] + b_hh[512 + colH];
            float bo = b_ih[768 + colH] + b_hh[768 + colH];
#pragma unroll
            for (int r = 0; r < 4; ++r) {
                int row = q * 4 + r;
                float ig = sigmf(acc[0][r] + bi);
                float fg = sigmf(acc[1][r] + bf2);
                float gg = tanhf(acc[2][r] + bg);
                float og = sigmf(acc[3][r] + bo);
                float cn = fg * sh_c[row * 257 + colH] + ig * gg;
                sh_c[row * 257 + colH] = cn;
                sh_h[row * 257 + colH] = og * tanhf(cn);
            }
        }
        __syncthreads();  // bar E (protects sh_inbf/sh_hbf/sh_h for next step)
    }
}

__global__ void rits_finalize(const float* __restrict__ lossbuf, float* __restrict__ out) {
    __shared__ float m1[Tz], m2[Tz], m3[Tz];
    int t = threadIdx.x;
    if (t < Tz) {
        float s0 = 0.0f, s1 = 0.0f, s2 = 0.0f, s3 = 0.0f;
        for (int g = 0; g < GRID; ++g) {
            const float* lb = lossbuf + ((size_t)g * Tz + t) * 4;
            s0 += lb[0]; s1 += lb[1]; s2 += lb[2]; s3 += lb[3];
        }
        float inv = 1.0f / (s0 + 1e-9f);
        m1[t] = s1 * inv; m2[t] = s2 * inv; m3[t] = s3 * inv;
    }
    __syncthreads();
    if (t == 0) {
        float rm = 0.0f, rl = 0.0f;
        for (int i = 0; i < Tz; ++i) {  // literal replay of reference accumulation
            rl += m1[i]; rl += m2[i]; rm += m3[i]; rl += rm;
        }
        out[(size_t)Bz * Tz * Fz] = rm / (float)Tz;
        out[(size_t)Bz * Tz * Fz + 1] = rl / (3.0f * (float)Tz);
    }
}

extern "C" void kernel_launch(void* const* d_in, const int* in_sizes, int n_in,
                              void* d_out, int out_size, void* d_ws, size_t ws_size,
                              hipStream_t stream) {
    const float* X = (const float*)d_in[0];
    const float* Mm = (const float*)d_in[1];
    const float* Dd = (const float*)d_in[2];
    const float* Wdh = (const float*)d_in[3];
    const float* b_dh = (const float*)d_in[4];
    const float* Wdx = (const float*)d_in[5];
    const float* b_dx = (const float*)d_in[6];
    const float* Whist = (const float*)d_in[7];
    const float* b_hist = (const float*)d_in[8];
    const float* Wfeat = (const float*)d_in[9];
    const float* b_feat = (const float*)d_in[10];
    const float* Wcomb = (const float*)d_in[11];
    const float* b_comb = (const float*)d_in[12];
    const float* Wih = (const float*)d_in[13];
    const float* b_ih = (const float*)d_in[14];
    const float* Whh = (const float*)d_in[15];
    const float* b_hh = (const float*)d_in[16];
    float* out = (float*)d_out;

    bf16* wsbf = (bf16*)d_ws;
    float* wdxd = (float*)((char*)d_ws + (size_t)438272 * 2);
    float* lossbuf = wdxd + 64;

    rits_convert<<<1712, 256, 0, stream>>>(Wdh, Wdx, Whist, Wfeat, Wcomb, Wih, Whh, wsbf, wdxd);
    rits_main<<<GRID, 1024, 0, stream>>>(X, Mm, Dd, b_dh, b_dx, b_hist, b_feat, b_comb, b_ih, b_hh,
                                         wsbf + 0, wsbf + 16384, wsbf + 32768, wsbf + 36864,
                                         wsbf + 45056, wsbf + 176128, wdxd, lossbuf, out);
    rits_finalize<<<1, 128, 0, stream>>>(lossbuf, out);
}